// Round 1
// baseline (387.158 us; speedup 1.0000x reference)
//
#include <hip/hip_runtime.h>

// Fused axial attention (RoadTransformer block), fp32, one block per b = n*64+w.
// Phases: [load] -> [P1: qkv GEMM + BN] -> per group-pair: [P3: logits+softmax] -> [P4: sv/sve + out BN].

__global__ __launch_bounds__(512, 1)
void fused_axial(const float* __restrict__ x,
                 const float* __restrict__ w_qkv,
                 const float* __restrict__ rel,
                 const float* __restrict__ bn_qkv,
                 const float* __restrict__ bn_sim,
                 const float* __restrict__ bn_out,
                 float* __restrict__ out) {
  constexpr float EPS = 1e-5f;
  // qkv_t[h][o]: transposed qkv, stride 260 (pad 4) -> b128 reads at 8-phase floor
  __shared__ __align__(16) float qkv_t[64][260];
  // relQ[d][c]: c<8 -> rel[c][d] (for qr, d=i-j+63); c in 8..15 -> rel[c][126-d] (for kr, same d!)
  __shared__ __align__(16) float relQ[127][20];
  // relV[d][c] = rel[16+c][d] (for sve, d=i-j+63)
  __shared__ __align__(16) float relV[127][20];
  // union: xs[128][64] (phase 1) / p_s[2][64][65] (phases 3-4)
  __shared__ __align__(16) float ps_xs[8320];
  __shared__ float s_qkv[256], t_qkv[256], s_out[256], t_out[256];
  __shared__ float s_sim[24], tsf[24];

  const int b = blockIdx.x;
  const int n = b >> 6;
  const int w = b & 63;
  const int tid = threadIdx.x;
  const int wv = tid >> 6;
  const int lane = tid & 63;

  // ---- loads ----
  const float* xb = x + n * 524288 + w;           // x[n][c][h][w], stride c:4096, h:64
  for (int idx = tid; idx < 8192; idx += 512) {
    const int c = idx >> 6, h = idx & 63;
    ps_xs[idx] = xb[c * 4096 + h * 64];           // xs[c][h]
  }
  for (int idx = tid; idx < 2032; idx += 512) {   // 127*16
    const int d = idx >> 4, c = idx & 15;
    relQ[d][c] = (c < 8) ? rel[c * 127 + d] : rel[c * 127 + 126 - d];
    relV[d][c] = rel[(16 + c) * 127 + d];
  }
  if (tid < 256) {
    float ga = bn_qkv[tid], be = bn_qkv[256 + tid], mu = bn_qkv[512 + tid], va = bn_qkv[768 + tid];
    float s = ga * rsqrtf(va + EPS);
    s_qkv[tid] = s;
    t_qkv[tid] = be - mu * s;
    ga = bn_out[tid]; be = bn_out[256 + tid]; mu = bn_out[512 + tid]; va = bn_out[768 + tid];
    s = ga * rsqrtf(va + EPS);
    s_out[tid] = s;
    t_out[tid] = be - mu * s;
  } else if (tid < 280) {
    const int c = tid - 256;
    const float ga = bn_sim[c], be = bn_sim[24 + c], mu = bn_sim[48 + c], va = bn_sim[72 + c];
    const float s = ga * rsqrtf(va + EPS);
    s_sim[c] = s;
    tsf[c] = be - mu * s;
  }
  __syncthreads();

  // ---- Phase 1: qkv_t[h][o] = BN(sum_c w[o][c] * xs[c][h]) ----
  {
    const int o0base = __builtin_amdgcn_readfirstlane(wv) * 32;  // wave-uniform scalar
    for (int og = 0; og < 8; ++og) {
      const int o0 = o0base + og * 4;
      const float* wr = w_qkv + o0 * 128;         // scalar base -> s_load
      float a0 = 0.f, a1 = 0.f, a2 = 0.f, a3 = 0.f;
      #pragma unroll 8
      for (int c = 0; c < 128; ++c) {
        const float xv = ps_xs[c * 64 + lane];
        a0 = fmaf(wr[c], xv, a0);
        a1 = fmaf(wr[128 + c], xv, a1);
        a2 = fmaf(wr[256 + c], xv, a2);
        a3 = fmaf(wr[384 + c], xv, a3);
      }
      qkv_t[lane][o0 + 0] = s_qkv[o0 + 0] * a0 + t_qkv[o0 + 0];
      qkv_t[lane][o0 + 1] = s_qkv[o0 + 1] * a1 + t_qkv[o0 + 1];
      qkv_t[lane][o0 + 2] = s_qkv[o0 + 2] * a2 + t_qkv[o0 + 2];
      qkv_t[lane][o0 + 3] = s_qkv[o0 + 3] * a3 + t_qkv[o0 + 3];
    }
  }
  __syncthreads();

  const int slot = wv >> 2;   // waves 0-3 -> group gp*2, waves 4-7 -> gp*2+1
  const int qw = wv & 3;

  for (int gp = 0; gp < 4; ++gp) {
    const int g = gp * 2 + slot;
    const int gc = g * 32;

    // ---- Phase 3: logits + softmax. lane = j; this wave does rows qw*16..qw*16+15 ----
    const float4 ka = *reinterpret_cast<const float4*>(&qkv_t[lane][gc + 8]);   // k[g][0..3][j]
    const float4 kb = *reinterpret_cast<const float4*>(&qkv_t[lane][gc + 12]);  // k[g][4..7][j]
    const float sqk = s_sim[g], sqr = s_sim[8 + g], skr = s_sim[16 + g];
    const float tg = tsf[g] + tsf[8 + g] + tsf[16 + g];
    for (int r = 0; r < 16; ++r) {
      const int i = qw * 16 + r;
      const float4 qa = *reinterpret_cast<const float4*>(&qkv_t[i][gc]);        // uniform
      const float4 qb = *reinterpret_cast<const float4*>(&qkv_t[i][gc + 4]);
      const int d = i - lane + 63;                                              // 0..126
      const float4 ra = *reinterpret_cast<const float4*>(&relQ[d][0]);
      const float4 rb = *reinterpret_cast<const float4*>(&relQ[d][4]);
      const float4 rc = *reinterpret_cast<const float4*>(&relQ[d][8]);
      const float4 rd = *reinterpret_cast<const float4*>(&relQ[d][12]);
      const float qk = qa.x*ka.x + qa.y*ka.y + qa.z*ka.z + qa.w*ka.w
                     + qb.x*kb.x + qb.y*kb.y + qb.z*kb.z + qb.w*kb.w;
      const float qr = qa.x*ra.x + qa.y*ra.y + qa.z*ra.z + qa.w*ra.w
                     + qb.x*rb.x + qb.y*rb.y + qb.z*rb.z + qb.w*rb.w;
      const float kr = ka.x*rc.x + ka.y*rc.y + ka.z*rc.z + ka.w*rc.w
                     + kb.x*rd.x + kb.y*rd.y + kb.z*rd.z + kb.w*rd.w;
      const float logit = sqk * qk + sqr * qr + skr * kr + tg;
      float mx = logit;
      #pragma unroll
      for (int off = 32; off > 0; off >>= 1) mx = fmaxf(mx, __shfl_xor(mx, off));
      const float e = __expf(logit - mx);
      float sm = e;
      #pragma unroll
      for (int off = 32; off > 0; off >>= 1) sm += __shfl_xor(sm, off);
      ps_xs[slot * 4160 + i * 65 + lane] = e / sm;
    }
    __syncthreads();

    // ---- Phase 4: sv/sve. lane = i; this wave does channels c0..c0+3 of group g ----
    const int c0 = qw * 4;
    float sv0=0.f, sv1=0.f, sv2=0.f, sv3=0.f, se0=0.f, se1=0.f, se2=0.f, se3=0.f;
    for (int j = 0; j < 64; ++j) {
      const float pv = ps_xs[slot * 4160 + lane * 65 + j];
      const float4 vj = *reinterpret_cast<const float4*>(&qkv_t[j][gc + 16 + c0]); // uniform
      const int d = lane - j + 63;
      const float4 rv = *reinterpret_cast<const float4*>(&relV[d][c0]);
      sv0 = fmaf(pv, vj.x, sv0); sv1 = fmaf(pv, vj.y, sv1);
      sv2 = fmaf(pv, vj.z, sv2); sv3 = fmaf(pv, vj.w, sv3);
      se0 = fmaf(pv, rv.x, se0); se1 = fmaf(pv, rv.y, se1);
      se2 = fmaf(pv, rv.z, se2); se3 = fmaf(pv, rv.w, se3);
    }
    {
      const float svv[4] = {sv0, sv1, sv2, sv3};
      const float sev[4] = {se0, se1, se2, se3};
      const int p0 = g * 16 + c0;
      #pragma unroll
      for (int k2 = 0; k2 < 4; ++k2) {
        const int p = p0 + k2;
        out[(n * 128 + p) * 4096 + lane * 64 + w] =
            s_out[2 * p] * svv[k2] + t_out[2 * p]
          + s_out[2 * p + 1] * sev[k2] + t_out[2 * p + 1];
      }
    }
    __syncthreads();
  }
}

extern "C" void kernel_launch(void* const* d_in, const int* in_sizes, int n_in,
                              void* d_out, int out_size, void* d_ws, size_t ws_size,
                              hipStream_t stream) {
  const float* x      = (const float*)d_in[0];
  const float* w_qkv  = (const float*)d_in[1];
  const float* rel    = (const float*)d_in[2];
  const float* bn_qkv = (const float*)d_in[3];
  const float* bn_sim = (const float*)d_in[4];
  const float* bn_out = (const float*)d_in[5];
  float* out = (float*)d_out;
  fused_axial<<<1024, 512, 0, stream>>>(x, w_qkv, rel, bn_qkv, bn_sim, bn_out, out);
}

// Round 3
// 309.174 us; speedup vs baseline: 1.2522x; 1.2522x over previous
//
#include <hip/hip_runtime.h>

// Fused axial attention (RoadTransformer), fp32, one block per b = n*64+w.
// R2 (resubmit after infra failure): no-max softmax (normalize in phase 4),
// register-blocked phase-1 GEMM, vectorized LDS traffic, XCD-chunked swizzle.

__global__ __launch_bounds__(512, 1)
void fused_axial(const float* __restrict__ x,
                 const float* __restrict__ w_qkv,
                 const float* __restrict__ rel,
                 const float* __restrict__ bn_qkv,
                 const float* __restrict__ bn_sim,
                 const float* __restrict__ bn_out,
                 float* __restrict__ out) {
  constexpr float EPS = 1e-5f;
  __shared__ __align__(16) float qkv_t[64][260];   // qkv_t[h][o], 66.5 KB
  __shared__ __align__(16) float relQ[127][20];    // c<8: rel[c][d]; c in 8..15: rel[c][126-d]
  __shared__ __align__(16) float relV[127][20];    // rel[16+c][d]
  __shared__ __align__(16) float UB[8704];         // union: xs[64][132] | p[2][64][68]
  __shared__ float s_qkv[256], t_qkv[256], s_out[256], t_out[256];
  __shared__ float s_sim[24];

  // XCD-chunked swizzle: consecutive work-ids (w-neighbors sharing x lines) on one XCD
  const int bid = blockIdx.x;
  const int b = (bid & 7) * 128 + (bid >> 3);
  const int n = b >> 6;
  const int w = b & 63;
  const int tid = threadIdx.x;
  const int wv = tid >> 6;
  const int lane = tid & 63;

  // ---- loads ----
  const float* xb = x + n * 524288 + w;            // x[n][c][h][w]: c stride 4096, h stride 64
  for (int idx = tid; idx < 8192; idx += 512) {
    const int c = idx >> 6, h = idx & 63;
    UB[h * 132 + c] = xb[c * 4096 + h * 64];       // xs[h][c]
  }
  for (int idx = tid; idx < 2032; idx += 512) {    // 127*16
    const int d = idx >> 4, c = idx & 15;
    relQ[d][c] = (c < 8) ? rel[c * 127 + d] : rel[c * 127 + 126 - d];
    relV[d][c] = rel[(16 + c) * 127 + d];
  }
  if (tid < 256) {
    float ga = bn_qkv[tid], be = bn_qkv[256 + tid], mu = bn_qkv[512 + tid], va = bn_qkv[768 + tid];
    float s = ga * rsqrtf(va + EPS);
    s_qkv[tid] = s;
    t_qkv[tid] = be - mu * s;
    ga = bn_out[tid]; be = bn_out[256 + tid]; mu = bn_out[512 + tid]; va = bn_out[768 + tid];
    s = ga * rsqrtf(va + EPS);
    s_out[tid] = s;
    t_out[tid] = be - mu * s;
  } else if (tid < 280) {
    const int c = tid - 256;
    s_sim[c] = bn_sim[c] * rsqrtf(bn_sim[72 + c] + EPS);   // shift cancels in softmax
  }
  __syncthreads();

  // ---- Phase 1: qkv_t[h][o] = BN(sum_c w[o][c] * xs[h][c]); 32 outputs per wave, one xs pass ----
  {
    const int o0 = __builtin_amdgcn_readfirstlane(wv) * 32;
    float acc[32];
    #pragma unroll
    for (int o = 0; o < 32; ++o) acc[o] = 0.f;
    const float* xr = &UB[lane * 132];
    for (int c0 = 0; c0 < 128; c0 += 4) {
      const float4 xv = *reinterpret_cast<const float4*>(xr + c0);
      const float* wp = w_qkv + o0 * 128 + c0;     // wave-uniform -> s_load
      #pragma unroll
      for (int o = 0; o < 32; ++o) {
        const float4 w4 = *reinterpret_cast<const float4*>(wp + o * 128);
        acc[o] = fmaf(w4.x, xv.x, acc[o]);
        acc[o] = fmaf(w4.y, xv.y, acc[o]);
        acc[o] = fmaf(w4.z, xv.z, acc[o]);
        acc[o] = fmaf(w4.w, xv.w, acc[o]);
      }
    }
    #pragma unroll
    for (int o = 0; o < 32; ++o) {
      const int oo = o0 + o;
      qkv_t[lane][oo] = s_qkv[oo] * acc[o] + t_qkv[oo];
    }
  }
  __syncthreads();

  const int slot = wv >> 2;           // waves 0-3: group gp*2; waves 4-7: gp*2+1
  const int qw = wv & 3;
  float* const pbase = &UB[slot * 4352];

  for (int gp = 0; gp < 4; ++gp) {
    const int g = gp * 2 + slot;
    const int gc = g * 32;

    // ---- Phase 3: e = exp(logit); lane = j, rows i = qw*16..qw*16+15 ----
    const float4 ka = *reinterpret_cast<const float4*>(&qkv_t[lane][gc + 8]);
    const float4 kb = *reinterpret_cast<const float4*>(&qkv_t[lane][gc + 12]);
    const float sqk = s_sim[g], sqr = s_sim[8 + g], skr = s_sim[16 + g];
    #pragma unroll 4
    for (int r = 0; r < 16; ++r) {
      const int i = qw * 16 + r;
      const float4 qa = *reinterpret_cast<const float4*>(&qkv_t[i][gc]);      // uniform
      const float4 qb = *reinterpret_cast<const float4*>(&qkv_t[i][gc + 4]);
      const int d = i - lane + 63;                                            // 0..126
      const float4 ra = *reinterpret_cast<const float4*>(&relQ[d][0]);
      const float4 rb = *reinterpret_cast<const float4*>(&relQ[d][4]);
      const float4 rc = *reinterpret_cast<const float4*>(&relQ[d][8]);
      const float4 rd = *reinterpret_cast<const float4*>(&relQ[d][12]);
      float qk = qa.x * ka.x;
      qk = fmaf(qa.y, ka.y, qk); qk = fmaf(qa.z, ka.z, qk); qk = fmaf(qa.w, ka.w, qk);
      qk = fmaf(qb.x, kb.x, qk); qk = fmaf(qb.y, kb.y, qk);
      qk = fmaf(qb.z, kb.z, qk); qk = fmaf(qb.w, kb.w, qk);
      float qr = qa.x * ra.x;
      qr = fmaf(qa.y, ra.y, qr); qr = fmaf(qa.z, ra.z, qr); qr = fmaf(qa.w, ra.w, qr);
      qr = fmaf(qb.x, rb.x, qr); qr = fmaf(qb.y, rb.y, qr);
      qr = fmaf(qb.z, rb.z, qr); qr = fmaf(qb.w, rb.w, qr);
      float kr = ka.x * rc.x;
      kr = fmaf(ka.y, rc.y, kr); kr = fmaf(ka.z, rc.z, kr); kr = fmaf(ka.w, rc.w, kr);
      kr = fmaf(kb.x, rd.x, kr); kr = fmaf(kb.y, rd.y, kr);
      kr = fmaf(kb.z, rd.z, kr); kr = fmaf(kb.w, rd.w, kr);
      const float logit = fmaf(sqk, qk, fmaf(sqr, qr, skr * kr));
      pbase[i * 68 + lane] = __expf(logit);        // unnormalized; row const cancels
    }
    __syncthreads();

    // ---- Phase 4: sv/sve + denominator; lane = i, channels c0..c0+3 ----
    const int c0 = qw * 4;
    float s0=0.f,s1=0.f,s2=0.f,s3=0.f,e0=0.f,e1=0.f,e2=0.f,e3=0.f,psum=0.f;
    const float* prow = pbase + lane * 68;
    for (int j0 = 0; j0 < 64; j0 += 4) {
      const float4 p4 = *reinterpret_cast<const float4*>(prow + j0);
      psum += (p4.x + p4.y) + (p4.z + p4.w);
      #pragma unroll
      for (int jj = 0; jj < 4; ++jj) {
        const int j = j0 + jj;
        const float pv = (jj == 0) ? p4.x : (jj == 1) ? p4.y : (jj == 2) ? p4.z : p4.w;
        const float4 vj = *reinterpret_cast<const float4*>(&qkv_t[j][gc + 16 + c0]);  // uniform
        const float4 rv = *reinterpret_cast<const float4*>(&relV[lane - j + 63][c0]);
        s0 = fmaf(pv, vj.x, s0); s1 = fmaf(pv, vj.y, s1);
        s2 = fmaf(pv, vj.z, s2); s3 = fmaf(pv, vj.w, s3);
        e0 = fmaf(pv, rv.x, e0); e1 = fmaf(pv, rv.y, e1);
        e2 = fmaf(pv, rv.z, e2); e3 = fmaf(pv, rv.w, e3);
      }
    }
    const float inv = 1.0f / psum;
    {
      const float svv[4] = {s0, s1, s2, s3};
      const float sev[4] = {e0, e1, e2, e3};
      const int p0 = g * 16 + c0;
      #pragma unroll
      for (int k2 = 0; k2 < 4; ++k2) {
        const int p = p0 + k2;
        out[(n * 128 + p) * 4096 + lane * 64 + w] =
            fmaf(s_out[2 * p], inv * svv[k2], t_out[2 * p])
          + fmaf(s_out[2 * p + 1], inv * sev[k2], t_out[2 * p + 1]);
      }
    }
    __syncthreads();
  }
}

extern "C" void kernel_launch(void* const* d_in, const int* in_sizes, int n_in,
                              void* d_out, int out_size, void* d_ws, size_t ws_size,
                              hipStream_t stream) {
  const float* x      = (const float*)d_in[0];
  const float* w_qkv  = (const float*)d_in[1];
  const float* rel    = (const float*)d_in[2];
  const float* bn_qkv = (const float*)d_in[3];
  const float* bn_sim = (const float*)d_in[4];
  const float* bn_out = (const float*)d_in[5];
  float* out = (float*)d_out;
  fused_axial<<<1024, 512, 0, stream>>>(x, w_qkv, rel, bn_qkv, bn_sim, bn_out, out);
}